// Round 10
// baseline (501.742 us; speedup 1.0000x reference)
//
#include <hip/hip_runtime.h>
#include <hip/hip_bf16.h>

#define NIN 6
#define HIDN 64
#define NHEAD 4
#define DEGPAD 5   // deg[] stride = 32 words = 128 B line

// ---- bf16 pack (RNE) ----
__device__ __forceinline__ unsigned short f2bf(float f) {
    unsigned u = __float_as_uint(f);
    unsigned r = (u >> 16) & 1u;
    return (unsigned short)((u + 0x7fffu + r) >> 16);
}

// ========== encoder stage 1: hid = relu(x@w1 + b1), wave per node ==========
__global__ __launch_bounds__(256) void encode1_kernel(
    const float* __restrict__ x,
    const float* __restrict__ w1, const float* __restrict__ b1,
    float* __restrict__ hid, int N) {
    int t = blockIdx.x * blockDim.x + threadIdx.x;
    int n = t >> 6, j = t & 63;
    if (n >= N) return;
    float acc = b1[j];
#pragma unroll
    for (int i = 0; i < NIN; i++) acc += x[n * NIN + i] * w1[i * HIDN + j];
    hid[(size_t)n * HIDN + j] = acc > 0.f ? acc : 0.f;
}

// ===== 64x64 fp32 matmul, weight-stationary, wave-uniform row (fp32 out) ====
__global__ __launch_bounds__(256) void mm64_plain_kernel(
    const float* __restrict__ src, const float* __restrict__ W,
    const float* __restrict__ bias, float* __restrict__ dst, int N) {
    int j = threadIdx.x & 63;
    int wv = (blockIdx.x * blockDim.x + threadIdx.x) >> 6;
    int nw = (gridDim.x * blockDim.x) >> 6;

    float Wc[HIDN];
#pragma unroll
    for (int k = 0; k < HIDN; k++) Wc[k] = W[k * HIDN + j];
    float bj = bias[j];

    for (int n0 = wv; n0 < N; n0 += nw) {
        int n = __builtin_amdgcn_readfirstlane(n0);
        const float4* __restrict__ row = (const float4*)(src + (size_t)n * HIDN);
        float a0 = 0.f, a1 = 0.f, a2 = 0.f, a3 = 0.f;
#pragma unroll
        for (int kk = 0; kk < 16; kk++) {
            float4 r = row[kk];
            a0 += r.x * Wc[4 * kk];
            a1 += r.y * Wc[4 * kk + 1];
            a2 += r.z * Wc[4 * kk + 2];
            a3 += r.w * Wc[4 * kk + 3];
        }
        dst[(size_t)n * HIDN + j] = ((a0 + a1) + (a2 + a3)) + bj;
    }
}

// ===== same matmul, bf16 out (gather buffer) + a_s/a_d head dots ===========
__global__ __launch_bounds__(256) void mm64_attn_kernel(
    const float* __restrict__ src, const float* __restrict__ W,
    const float* __restrict__ att_s, const float* __restrict__ att_d,
    unsigned short* __restrict__ dst16,
    float* __restrict__ a_s, float* __restrict__ a_d, int N) {
    int j = threadIdx.x & 63;
    int wv = (blockIdx.x * blockDim.x + threadIdx.x) >> 6;
    int nw = (gridDim.x * blockDim.x) >> 6;

    float Wc[HIDN];
#pragma unroll
    for (int k = 0; k < HIDN; k++) Wc[k] = W[k * HIDN + j];
    float asj = att_s[j];
    float adj = att_d[j];

    for (int n0 = wv; n0 < N; n0 += nw) {
        int n = __builtin_amdgcn_readfirstlane(n0);
        const float4* __restrict__ row = (const float4*)(src + (size_t)n * HIDN);
        float a0 = 0.f, a1 = 0.f, a2 = 0.f, a3 = 0.f;
#pragma unroll
        for (int kk = 0; kk < 16; kk++) {
            float4 r = row[kk];
            a0 += r.x * Wc[4 * kk];
            a1 += r.y * Wc[4 * kk + 1];
            a2 += r.z * Wc[4 * kk + 2];
            a3 += r.w * Wc[4 * kk + 3];
        }
        float acc = (a0 + a1) + (a2 + a3);
        dst16[(size_t)n * HIDN + j] = f2bf(acc);
        float ts = acc * asj;
        float td = acc * adj;
#pragma unroll
        for (int o = 8; o > 0; o >>= 1) {
            ts += __shfl_xor(ts, o);
            td += __shfl_xor(td, o);
        }
        if ((j & 15) == 0) {
            a_s[(size_t)n * NHEAD + (j >> 4)] = ts;
            a_d[(size_t)n * NHEAD + (j >> 4)] = td;
        }
    }
}

// ====== tiny per-layer edge-attn constants: a_e[i,h] = eattr[i]*c1 + c0 =====
__global__ void consts_kernel(const float* __restrict__ w_ee, const float* __restrict__ b_ee,
                              const float* __restrict__ w_eg, const float* __restrict__ att_edge,
                              float* __restrict__ c1, float* __restrict__ c0) {
    int t = threadIdx.x;
    if (t >= 12) return;
    int l = t >> 2, hh = t & 3;
    float s1 = 0.f, s0 = 0.f;
    for (int j = 0; j < HIDN; j++) {
        float wj = 0.f;
        for (int d = 0; d < 16; d++)
            wj += w_eg[l * 4096 + j * 64 + hh * 16 + d] * att_edge[l * 64 + hh * 16 + d];
        s1 += w_ee[j] * wj;
        s0 += b_ee[j] * wj;
    }
    c1[l * 4 + hh] = s1;
    c0[l * 4 + hh] = s0;
}

// ======= CSR build: histogram(+rank) -> scan -> atomic-free scatter =========
// 8 edges/thread, strided: 8 independent atomics in flight per lane.
#define HB 8
__global__ __launch_bounds__(256) void hist_kernel(const int* __restrict__ ei,
                                                   unsigned* __restrict__ deg,
                                                   unsigned* __restrict__ rank, int E) {
    int t = blockIdx.x * 256 + threadIdx.x;
    int nt = gridDim.x * 256;
    int d[HB];
    unsigned r[HB];
#pragma unroll
    for (int k = 0; k < HB; k++) {
        int idx = t + k * nt;
        d[k] = (idx < E) ? ei[E + idx] : 0;
    }
#pragma unroll
    for (int k = 0; k < HB; k++) {
        int idx = t + k * nt;
        if (idx < E) r[k] = atomicAdd(&deg[(size_t)d[k] << DEGPAD], 1u);
    }
#pragma unroll
    for (int k = 0; k < HB; k++) {
        int idx = t + k * nt;
        if (idx < E) rank[idx] = r[k];
    }
}

__global__ __launch_bounds__(256) void scan1_kernel(const unsigned* __restrict__ deg,
                                                    unsigned* __restrict__ rp,
                                                    unsigned* __restrict__ bsum, int N) {
    __shared__ unsigned sm[256];
    int t = threadIdx.x, i = blockIdx.x * 256 + t;
    unsigned v = (i < N) ? deg[(size_t)i << DEGPAD] : 0u;
    sm[t] = v;
    __syncthreads();
    unsigned x = v;
    for (int o = 1; o < 256; o <<= 1) {
        unsigned add = (t >= o) ? sm[t - o] : 0u;
        __syncthreads();
        x += add; sm[t] = x;
        __syncthreads();
    }
    if (i < N) rp[i] = x - v;
    if (t == 255) bsum[blockIdx.x] = x;
}

__global__ void scan2_kernel(const unsigned* __restrict__ bsum,
                             unsigned* __restrict__ boff, int nb) {
    __shared__ unsigned sm[1024];
    int t = threadIdx.x;
    unsigned v = (t < nb) ? bsum[t] : 0u;
    sm[t] = v;
    __syncthreads();
    unsigned x = v;
    for (int o = 1; o < 1024; o <<= 1) {
        unsigned add = (t >= o) ? sm[t - o] : 0u;
        __syncthreads();
        x += add; sm[t] = x;
        __syncthreads();
    }
    if (t < nb) boff[t] = x - v;
}

__global__ __launch_bounds__(256) void scan3_kernel(unsigned* __restrict__ rp,
                                                    const unsigned* __restrict__ boff,
                                                    int N, int E) {
    int i = blockIdx.x * 256 + threadIdx.x;
    if (i < N) rp[i] = rp[i] + boff[blockIdx.x];
    if (i == 0) rp[N] = (unsigned)E;
}

// one packed 8B store per edge; no atomics; 4 edges/thread for MLP
#define SB 4
__global__ __launch_bounds__(256) void csr_scatter_kernel(
    const int* __restrict__ ei, const float* __restrict__ eattr,
    const unsigned* __restrict__ rp, const unsigned* __restrict__ rank,
    int2* __restrict__ eca, int E) {
    int t = blockIdx.x * 256 + threadIdx.x;
    int nt = gridDim.x * 256;
    int s[SB], d[SB];
    float a[SB];
    unsigned rk[SB], rpv[SB];
#pragma unroll
    for (int k = 0; k < SB; k++) {
        int idx = t + k * nt;
        if (idx < E) {
            s[k] = ei[idx];
            d[k] = ei[E + idx];
            a[k] = eattr[idx];
            rk[k] = rank[idx];
        }
    }
#pragma unroll
    for (int k = 0; k < SB; k++) {
        int idx = t + k * nt;
        if (idx < E) rpv[k] = rp[d[k]];
    }
#pragma unroll
    for (int k = 0; k < SB; k++) {
        int idx = t + k * nt;
        if (idx < E) eca[rpv[k] + rk[k]] = make_int2(s[k], __float_as_int(a[k]));
    }
}

// ===== fused per-layer edge pipeline: 4 dst nodes per wave =================
__global__ __launch_bounds__(256) void gat_fused_kernel(
    const unsigned* __restrict__ rp, const int2* __restrict__ eca,
    const unsigned short* __restrict__ hw16,
    const float* __restrict__ a_s, const float* __restrict__ a_d,
    const float* __restrict__ c1, const float* __restrict__ c0,
    float* __restrict__ h, const float* __restrict__ bg,
    const float* __restrict__ g, const float* __restrict__ b, int N) {
    __shared__ float exl[4 * 272];
    __shared__ int srl[4 * 68];
    int t = blockIdx.x * blockDim.x + threadIdx.x;
    int lane = t & 63;
    int q = lane >> 4;
    int l = lane & 15;
    int hd = l >> 2;
    int sub = l & 3;
    int n = ((t >> 6) << 2) + q;
    int wslot = (threadIdx.x >> 6);
    float* myex = exl + wslot * 272 + 68 * q;
    int* mysrc = srl + wslot * 68 + 17 * q;

    bool nv = n < N;
    unsigned beg = nv ? rp[n] : 0u;
    int deg = nv ? (int)(rp[n + 1] - beg) : 0;

    float4 ad4 = nv ? *(const float4*)(a_d + ((size_t)n << 2)) : make_float4(0, 0, 0, 0);
    float4 C1 = *(const float4*)c1;
    float4 C0 = *(const float4*)c0;

    int md = deg;
    md = max(md, __shfl_xor(md, 16));
    md = max(md, __shfl_xor(md, 32));
    int chunks = (md + 15) >> 4;

    const unsigned* __restrict__ hwp = (const unsigned*)hw16;
    unsigned loff = (unsigned)(l << 1);

    float ssum = 0.f;
    float ac0 = 0.f, ac1 = 0.f, ac2 = 0.f, ac3 = 0.f;

    for (int k = 0; k < chunks; k++) {
        int i = (k << 4) + l;
        bool act = i < deg;
        int2 ce = act ? eca[beg + i] : make_int2(0, 0);
        int src = ce.x;
        float ea = __int_as_float(ce.y);
        float4 as4 = act ? *(const float4*)(a_s + ((size_t)src << 2))
                         : make_float4(0, 0, 0, 0);
        float s0 = as4.x + ad4.x + ea * C1.x + C0.x;
        float s1 = as4.y + ad4.y + ea * C1.y + C0.y;
        float s2 = as4.z + ad4.z + ea * C1.z + C0.z;
        float s3 = as4.w + ad4.w + ea * C1.w + C0.w;
        s0 = s0 >= 0.f ? s0 : 0.2f * s0;
        s1 = s1 >= 0.f ? s1 : 0.2f * s1;
        s2 = s2 >= 0.f ? s2 : 0.2f * s2;
        s3 = s3 >= 0.f ? s3 : 0.2f * s3;
        float e0 = act ? __expf(s0) : 0.f;
        float e1 = act ? __expf(s1) : 0.f;
        float e2 = act ? __expf(s2) : 0.f;
        float e3 = act ? __expf(s3) : 0.f;
        *(float4*)(myex + (l << 2)) = make_float4(e0, e1, e2, e3);
        mysrc[l] = act ? src : 0;

        float w0 = myex[(sub << 2) + hd];
        float w1 = myex[((sub + 4) << 2) + hd];
        float w2 = myex[((sub + 8) << 2) + hd];
        float w3 = myex[((sub + 12) << 2) + hd];
        float csum = (w0 + w1) + (w2 + w3);
        csum += __shfl_xor(csum, 1);
        csum += __shfl_xor(csum, 2);
        ssum += csum;

#pragma unroll
        for (int e = 0; e < 16; e++) {
            float w = myex[(e << 2) + hd];
            int so = mysrc[e];
            uint2 uu = *(const uint2*)(hwp + (((unsigned)so << 5) + loff));
            ac0 += w * __uint_as_float(uu.x << 16);
            ac1 += w * __uint_as_float(uu.x & 0xffff0000u);
            ac2 += w * __uint_as_float(uu.y << 16);
            ac3 += w * __uint_as_float(uu.y & 0xffff0000u);
        }
    }

    if (!nv) return;
    float inv = 1.f / (ssum + 1e-16f);
    float4 bg4 = *(const float4*)(bg + (l << 2));
    float4 hv4 = *(const float4*)(h + (size_t)n * HIDN + (l << 2));

    float a0 = ac0 * inv + bg4.x;
    float a1 = ac1 * inv + bg4.y;
    float a2 = ac2 * inv + bg4.z;
    float a3 = ac3 * inv + bg4.w;
    a0 = a0 > 0.f ? a0 : (__expf(a0) - 1.f);
    a1 = a1 > 0.f ? a1 : (__expf(a1) - 1.f);
    a2 = a2 > 0.f ? a2 : (__expf(a2) - 1.f);
    a3 = a3 > 0.f ? a3 : (__expf(a3) - 1.f);
    float v0 = hv4.x + a0, v1 = hv4.y + a1, v2 = hv4.z + a2, v3 = hv4.w + a3;

    float s = (v0 + v1) + (v2 + v3);
    float sq = (v0 * v0 + v1 * v1) + (v2 * v2 + v3 * v3);
#pragma unroll
    for (int o = 8; o > 0; o >>= 1) {
        s += __shfl_xor(s, o);
        sq += __shfl_xor(sq, o);
    }
    float mean = s * (1.f / 64.f);
    float var = sq * (1.f / 64.f) - mean * mean;
    float rr = rsqrtf(var + 1e-5f);
    float4 g4 = *(const float4*)(g + (l << 2));
    float4 b4 = *(const float4*)(b + (l << 2));
    float4 outv;
    outv.x = (v0 - mean) * rr * g4.x + b4.x;
    outv.y = (v1 - mean) * rr * g4.y + b4.y;
    outv.z = (v2 - mean) * rr * g4.z + b4.z;
    outv.w = (v3 - mean) * rr * g4.w + b4.w;
    *(float4*)(h + (size_t)n * HIDN + (l << 2)) = outv;
}

extern "C" void kernel_launch(void* const* d_in, const int* in_sizes, int n_in,
                              void* d_out, int out_size, void* d_ws, size_t ws_size,
                              hipStream_t stream) {
    const float* x      = (const float*)d_in[0];
    const int*   ei     = (const int*)d_in[1];
    const float* eattr  = (const float*)d_in[2];
    const float* w_ne1  = (const float*)d_in[3];
    const float* b_ne1  = (const float*)d_in[4];
    const float* w_ne2  = (const float*)d_in[5];
    const float* b_ne2  = (const float*)d_in[6];
    const float* w_ee   = (const float*)d_in[7];
    const float* b_ee   = (const float*)d_in[8];
    const float* w_gat  = (const float*)d_in[9];
    const float* w_eg   = (const float*)d_in[10];
    const float* att_src= (const float*)d_in[11];
    const float* att_dst= (const float*)d_in[12];
    const float* att_edge=(const float*)d_in[13];
    const float* b_gat  = (const float*)d_in[14];
    const float* ln_g   = (const float*)d_in[15];
    const float* ln_b   = (const float*)d_in[16];
    const float* w_out  = (const float*)d_in[17];
    const float* b_out  = (const float*)d_in[18];

    const int N = in_sizes[0] / NIN;
    const int E = in_sizes[2];

    // -------- workspace layout --------
    float* ws   = (float*)d_ws;
    float* h    = ws;                                   // N*64
    float* hid  = h + (size_t)N * 64;                   // N*64
    unsigned short* hw16 = (unsigned short*)(hid + (size_t)N * 64);  // N*64 u16
    float* a_s  = (float*)(hw16 + (size_t)N * 64);      // N*4
    float* a_d  = a_s + (size_t)N * 4;                  // N*4
    float* c1   = a_d + (size_t)N * 4;                  // 12
    float* c0   = c1 + 12;                              // 12
    int2*  eca  = (int2*)(c0 + 12);                     // E int2
    unsigned* rank = (unsigned*)(eca + (size_t)E);      // E
    unsigned* deg  = rank + (size_t)E;                  // N<<DEGPAD (line-padded)
    unsigned* rp   = deg + ((size_t)N << DEGPAD);       // N+1
    unsigned* bsum = rp + (size_t)N + 1;                // <=1024
    unsigned* boff = bsum + 1024;                       // <=1024

    dim3 blk(256);
    int nodeWaveBlocks = (int)(((size_t)N * 64 + 255) / 256);
    int quadBlocks = (int)(((size_t)((N + 3) / 4) * 64 + 255) / 256);
    int nodeBlocks = (N + 255) / 256;
    int histBlocks = (E + HB * 256 - 1) / (HB * 256);
    int scatBlocks = (E + SB * 256 - 1) / (SB * 256);
    int mmBlocks = 2048;    // 8192 waves, grid-stride over nodes

    // -------- CSR build (rank from hist atomic; scatter atomic-free) -------
    hipMemsetAsync(deg, 0, ((size_t)N << DEGPAD) * sizeof(unsigned), stream);
    hist_kernel<<<histBlocks, blk, 0, stream>>>(ei, deg, rank, E);
    scan1_kernel<<<nodeBlocks, blk, 0, stream>>>(deg, rp, bsum, N);
    scan2_kernel<<<1, 1024, 0, stream>>>(bsum, boff, nodeBlocks);
    scan3_kernel<<<nodeBlocks, blk, 0, stream>>>(rp, boff, N, E);
    csr_scatter_kernel<<<scatBlocks, blk, 0, stream>>>(ei, eattr, rp, rank, eca, E);

    consts_kernel<<<1, 64, 0, stream>>>(w_ee, b_ee, w_eg, att_edge, c1, c0);

    // -------- encoder: hid = relu(x@w1+b1); h = hid@w2+b2 --------
    encode1_kernel<<<nodeWaveBlocks, blk, 0, stream>>>(x, w_ne1, b_ne1, hid, N);
    mm64_plain_kernel<<<mmBlocks, blk, 0, stream>>>(hid, w_ne2, b_ne2, h, N);

    // layer-0 transform
    mm64_attn_kernel<<<mmBlocks, blk, 0, stream>>>(
        h, w_gat, att_src, att_dst, hw16, a_s, a_d, N);

    for (int l = 0; l < 3; l++) {
        gat_fused_kernel<<<quadBlocks, blk, 0, stream>>>(
            rp, eca, hw16, a_s, a_d, c1 + l * 4, c0 + l * 4,
            h, b_gat + l * 64, ln_g + l * 64, ln_b + l * 64, N);
        if (l < 2) {
            mm64_attn_kernel<<<mmBlocks, blk, 0, stream>>>(
                h, w_gat + (size_t)(l + 1) * 4096,
                att_src + (l + 1) * 64, att_dst + (l + 1) * 64,
                hw16, a_s, a_d, N);
        }
    }
    // -------- output projection --------
    mm64_plain_kernel<<<mmBlocks, blk, 0, stream>>>(h, w_out, b_out, (float*)d_out, N);
}